// Round 3
// baseline (137.698 us; speedup 1.0000x reference)
//
#include <hip/hip_runtime.h>

// GCN layer: out = relu( segment_mean(feature[edge_src], edge_dst) @ W^T + b )
// N=100000 nodes, E=1200000 edges, 64 feats in/out, all f32.
//
// Round 17: restore memory-level parallelism in the ownership gather.
// r16's exclusive-ownership phase 4 removed atomics but serialized each slot
// into an ~18-edge dependent load chain (1-deep prefetch) -> aggregate was
// latency-bound at 2.35 TB/s / 29% peak. Now: row-batched 4-wide gather.
// Per CSR row, 4 parallel f32 partial sums fed by 4 independent fb16 loads
// per iteration; combined at flush as (s0+s1)+(s2+s3) (fixed expression,
// deterministic). Slot load-chain ~18*L -> ~5*L.
// Also: offsets table transposed to offTT[bucket][block] so aggregate's
// phase-0 segment map reads two contiguous 1KB rows instead of 256 strided
// cache lines (build scatter-writes it; L2 absorbs).

typedef __attribute__((ext_vector_type(8))) short short8;   // 8 bf16
typedef __attribute__((ext_vector_type(4))) float floatx4;  // MFMA acc

constexpr int kNodes = 100000;
constexpr int kEdges = 1200000;

constexpr int kBuckets = 1024;
constexpr int kBucketNodes = 98;                    // 1024*98 = 100352 >= N

constexpr int kBinBlocks = 256;
constexpr int kEdgesPerBlock = 4688;                // 256*4688 = 1200128 >= E
constexpr int kEPT = (kEdgesPerBlock + 1023) / 1024; // 5

constexpr int kCap = 2048;        // max edges/bucket (mean 1172, ~26 sigma)
constexpr int kAccStride = 68;    // writes at {c,16+c,32+c,48+c}

// Workspace layout (int elements). Total ~18.7 MB.
constexpr int kWsFeat   = 0;                        // uint2[1600000] (12.8MB)
constexpr int kWsOff    = 3200000;                  // int[1025][256] transposed
constexpr int kWsBinned = kWsOff + (kBuckets + 1) * kBinBlocks;  // int[256*4688]

__device__ __forceinline__ unsigned bf16rne(float f) {
  unsigned u = __float_as_uint(f);
  return (u + 0x7fffu + ((u >> 16) & 1u)) >> 16;  // round-to-nearest-even
}

// ---------------------------------------------------------------------------
// Kernel 1: feature conversion + single-pass deterministic bucket binning.
// offTT layout: offTT[bkt][blk] = exclusive start of bucket bkt within block
// blk's region; row kBuckets holds each block's edge count.
// ---------------------------------------------------------------------------
__global__ __launch_bounds__(1024) void gcn_build(
    const float* __restrict__ feat,
    const int* __restrict__ src, const int* __restrict__ dst,
    int* __restrict__ ws) {
  uint2* fb16 = (uint2*)(ws + kWsFeat);
  int* offTT  = ws + kWsOff;
  int* binned = ws + kWsBinned;

  __shared__ int lhist[kBuckets];
  __shared__ int lcur[kBuckets];
  __shared__ int wsum[16];

  const int tid = threadIdx.x;
  lhist[tid] = 0;
  __syncthreads();

  // ---- edge slice load + bucket histogram ----
  const int e0 = blockIdx.x * kEdgesPerBlock;
  const int cnt = min(kEdgesPerBlock, kEdges - e0);   // last block: 4560
  int es[kEPT], ebk[kEPT], edl[kEPT];
  #pragma unroll
  for (int k = 0; k < kEPT; ++k) {
    const int j = tid + k * 1024;
    if (j < cnt) {
      es[k] = src[e0 + j];
      const int d = dst[e0 + j];
      const int bk = d / kBucketNodes;      // magic-multiply const div
      ebk[k] = bk;
      edl[k] = d - bk * kBucketNodes;
      atomicAdd(&lhist[bk], 1);
    }
  }

  // ---- feature f32 -> permuted bf16 (independent; overlaps hist latency) ----
  const int t = blockIdx.x * 1024 + tid;
  for (int i = t; i < kNodes * 16; i += kBinBlocks * 1024) {
    const float* fr = feat + (size_t)(i >> 4) * 64 + (i & 15);
    uint2 p;
    p.x = bf16rne(fr[0])  | (bf16rne(fr[16]) << 16);
    p.y = bf16rne(fr[32]) | (bf16rne(fr[48]) << 16);
    fb16[i] = p;
  }
  __syncthreads();

  // ---- two-level shfl exclusive scan over 1024 counts ----
  const int own = lhist[tid];
  const int wv = tid >> 6, ln = tid & 63;
  int sc = own;
  #pragma unroll
  for (int off = 1; off < 64; off <<= 1) {
    const int v = __shfl_up(sc, off, 64);
    if (ln >= off) sc += v;
  }
  if (ln == 63) wsum[wv] = sc;            // wave totals
  __syncthreads();
  if (tid < 64) {
    int tw = (tid < 16) ? wsum[tid] : 0;
    #pragma unroll
    for (int off = 1; off < 16; off <<= 1) {
      const int v = __shfl_up(tw, off, 64);
      if (tid >= off) tw += v;
    }
    if (tid < 16) wsum[tid] = tw;          // inclusive wave prefix
  }
  __syncthreads();
  const int excl = sc - own + (wv ? wsum[wv - 1] : 0);
  lcur[tid] = excl;
  offTT[tid * kBinBlocks + blockIdx.x] = excl;   // transposed (L2 combines)
  if (tid == 0) offTT[kBuckets * kBinBlocks + blockIdx.x] = cnt;
  __syncthreads();

  // ---- rank + scatter into this block's bucket-grouped region ----
  int* myBin = binned + blockIdx.x * kEdgesPerBlock;
  #pragma unroll
  for (int k = 0; k < kEPT; ++k) {
    const int j = tid + k * 1024;
    if (j < cnt) {
      const int pos = atomicAdd(&lcur[ebk[k]], 1);  // LDS int atomic
      myBin[pos] = es[k] | (edl[k] << 17);
    }
  }
}

// ---------------------------------------------------------------------------
// Kernel 2: one block per bucket (1024 blocks), 1024 threads (16 waves),
// pinned 2 blocks/CU.
//  0) segment map over the 256 block regions (two contiguous offTT rows)
//  1) local-dst histogram (edge words cached in registers, <=2/thread)
//  2) wave-0 shfl scan of 128 counters (98 live) -> lofs[]
//  3) rank+scatter into lsrc[] (CSR sorted by dL) + slot row-partition
//  4) exclusive-ownership gather, row-batched 4-wide MLP, no atomics
//  5) f32 sums -> bf16 mean rows in hsAll (98 rows live, 112 allocated)
//  6) MFMA epilogue (waves 0..6): 16-node tiles, guard local<98.
// ---------------------------------------------------------------------------
__global__ __launch_bounds__(1024, 8) void gcn_aggregate(
    const int*   __restrict__ ws_in,
    const float* __restrict__ W,     // [64][64] row-major W[o][d]
    const float* __restrict__ b,     // [64]
    float*       __restrict__ out) { // [kNodes][64]
  const uint2* fb16 = (const uint2*)(ws_in + kWsFeat);
  const int* offTT  = ws_in + kWsOff;
  const int* binned = ws_in + kWsBinned;

  // lsrc (8KB, phases 1-4) and hsAll (16.1KB, phases 5-6) share storage.
  __shared__ __align__(16) char uShared[112 * 72 * 2];   // 16128 B
  __shared__ __align__(16) int accum[kBucketNodes * kAccStride]; // f32 bits
  __shared__ int    lofs[129];
  __shared__ int    lcur[128];
  __shared__ int    slotR[65];
  __shared__ int    runL[kBinBlocks + 1];
  __shared__ int    runG[kBinBlocks];
  __shared__ int    ssm[kBinBlocks];
  __shared__ ushort Wb16[64 * 64];                 // 8 KB, natural W[o][d]
  __shared__ float  bsh[64];
  int*    lsrc  = (int*)uShared;
  ushort* hsAll = (ushort*)uShared;

  const int tid = threadIdx.x;
  const int bkt = blockIdx.x;

  if (tid < 128) lcur[tid] = 0;
  for (int i = tid; i < 4096; i += 1024) Wb16[i] = (ushort)bf16rne(W[i]);
  if (tid < 64) bsh[tid] = b[tid];

  // ---- 0) segment map over the 256 block regions ----
  if (tid < kBinBlocks) {
    const int o0 = offTT[bkt * kBinBlocks + tid];         // contiguous row
    const int o1 = offTT[(bkt + 1) * kBinBlocks + tid];   // next row
    ssm[tid] = o1 - o0;
    runG[tid] = tid * kEdgesPerBlock + o0;
  }
  __syncthreads();
  if (tid < 64) {                        // wave-0 shfl scan, 4 elems/lane
    const int base = tid * 4;
    const int v0 = ssm[base], v1 = ssm[base + 1];
    const int v2 = ssm[base + 2], v3 = ssm[base + 3];
    const int p1 = v0 + v1, p2 = p1 + v2, tot = p2 + v3;
    int sc = tot;
    #pragma unroll
    for (int off = 1; off < 64; off <<= 1) {
      const int v = __shfl_up(sc, off, 64);
      if (tid >= off) sc += v;
    }
    const int ex = sc - tot;             // exclusive prefix of lane total
    runL[base]     = ex;
    runL[base + 1] = ex + v0;
    runL[base + 2] = ex + p1;
    runL[base + 3] = ex + p2;
    if (tid == 63) runL[kBinBlocks] = sc;
  }
  __syncthreads();

  int sz = runL[kBinBlocks];
  if (sz > kCap) sz = kCap;  // never hit for this dataset

  // j -> global binned index via 8-step binary search over runL
  auto mapRead = [&](int j) -> unsigned {
    int lo = 0, hi = kBinBlocks;
    #pragma unroll
    for (int it = 0; it < 8; ++it) {
      const int mid = (lo + hi) >> 1;
      if (runL[mid] <= j) lo = mid; else hi = mid;
    }
    return (unsigned)binned[runG[lo] + (j - runL[lo])];
  };

  // ---- 1) local-dst histogram; cache edge words in registers ----
  const int j0 = tid, j1 = tid + 1024;
  const bool va = j0 < sz, vb = j1 < sz;
  unsigned ea = 0, eb = 0;
  if (va) { ea = mapRead(j0); atomicAdd(&lcur[ea >> 17], 1); }
  if (vb) { eb = mapRead(j1); atomicAdd(&lcur[eb >> 17], 1); }
  __syncthreads();

  // ---- 2) exclusive scan of 128 counters by wave 0 (98 live) ----
  if (tid < 64) {
    const int a  = lcur[tid * 2];
    const int b2 = lcur[tid * 2 + 1];
    int s = a + b2;
    #pragma unroll
    for (int off = 1; off < 64; off <<= 1) {
      const int v = __shfl_up(s, off, 64);
      if (tid >= off) s += v;
    }
    const int ex1 = s - b2;
    const int ex0 = ex1 - a;
    lofs[tid * 2]     = ex0;
    lofs[tid * 2 + 1] = ex1;
    lcur[tid * 2]     = ex0;
    lcur[tid * 2 + 1] = ex1;
    if (tid == 63) lofs[128] = s;
  }
  __syncthreads();

  // ---- 3) rank+scatter into CSR (sorted by dL) + slot row-partition ----
  if (va) { const int p = atomicAdd(&lcur[ea >> 17], 1); lsrc[p] = (int)ea; }
  if (vb) { const int p = atomicAdd(&lcur[eb >> 17], 1); lsrc[p] = (int)eb; }
  // degree-weighted partition: slotR[s] = lower_bound(lofs[0..98], s*sz/64)
  if (tid < 64) {
    const int tgt = (sz * tid) >> 6;
    int lo = 0, hi = kBucketNodes;
    #pragma unroll
    for (int it = 0; it < 7; ++it) {
      const int mid = (lo + hi) >> 1;
      if (lofs[mid] < tgt) lo = mid + 1; else hi = mid;
    }
    slotR[tid] = lo;
  }
  if (tid == 64) slotR[64] = kBucketNodes;  // force full coverage (deg-0 tail)
  __syncthreads();

  // ---- 4) exclusive-ownership gather, row-batched 4-wide MLP ----
  const int wave = tid >> 6;
  const int lane = tid & 63;
  const int g = lane >> 4;   // slot within wave
  const int c = lane & 15;   // 8B chunk = feats {c,16+c,32+c,48+c}
  {
    const int slot = wave * 4 + g;           // 0..63
    const int rEnd = slotR[slot + 1];
    for (int r = slotR[slot]; r < rEnd; ++r) {
      const int jA = lofs[r];
      const int jB = lofs[r + 1];
      float s00 = 0.f, s01 = 0.f, s02 = 0.f, s03 = 0.f;
      float s10 = 0.f, s11 = 0.f, s12 = 0.f, s13 = 0.f;
      float s20 = 0.f, s21 = 0.f, s22 = 0.f, s23 = 0.f;
      float s30 = 0.f, s31 = 0.f, s32 = 0.f, s33 = 0.f;
      int j = jA;
      #pragma unroll 1
      for (; j + 4 <= jB; j += 4) {          // 4 independent loads in flight
        const unsigned e0 = (unsigned)lsrc[j];
        const unsigned e1 = (unsigned)lsrc[j + 1];
        const unsigned e2 = (unsigned)lsrc[j + 2];
        const unsigned e3 = (unsigned)lsrc[j + 3];
        const uint2 v0 = fb16[(size_t)(e0 & 0x1FFFFu) * 16 + c];
        const uint2 v1 = fb16[(size_t)(e1 & 0x1FFFFu) * 16 + c];
        const uint2 v2 = fb16[(size_t)(e2 & 0x1FFFFu) * 16 + c];
        const uint2 v3 = fb16[(size_t)(e3 & 0x1FFFFu) * 16 + c];
        s00 += __uint_as_float(v0.x << 16);
        s01 += __uint_as_float(v0.x & 0xffff0000u);
        s02 += __uint_as_float(v0.y << 16);
        s03 += __uint_as_float(v0.y & 0xffff0000u);
        s10 += __uint_as_float(v1.x << 16);
        s11 += __uint_as_float(v1.x & 0xffff0000u);
        s12 += __uint_as_float(v1.y << 16);
        s13 += __uint_as_float(v1.y & 0xffff0000u);
        s20 += __uint_as_float(v2.x << 16);
        s21 += __uint_as_float(v2.x & 0xffff0000u);
        s22 += __uint_as_float(v2.y << 16);
        s23 += __uint_as_float(v2.y & 0xffff0000u);
        s30 += __uint_as_float(v3.x << 16);
        s31 += __uint_as_float(v3.x & 0xffff0000u);
        s32 += __uint_as_float(v3.y << 16);
        s33 += __uint_as_float(v3.y & 0xffff0000u);
      }
      #pragma unroll 1
      for (; j < jB; ++j) {                  // remainder (<=3), fixed order
        const unsigned e = (unsigned)lsrc[j];
        const uint2 v = fb16[(size_t)(e & 0x1FFFFu) * 16 + c];
        s00 += __uint_as_float(v.x << 16);
        s01 += __uint_as_float(v.x & 0xffff0000u);
        s02 += __uint_as_float(v.y << 16);
        s03 += __uint_as_float(v.y & 0xffff0000u);
      }
      int* rp = accum + r * kAccStride + c;  // fixed combine -> deterministic
      rp[0]  = __float_as_int((s00 + s10) + (s20 + s30));
      rp[16] = __float_as_int((s01 + s11) + (s21 + s31));
      rp[32] = __float_as_int((s02 + s12) + (s22 + s32));
      rp[48] = __float_as_int((s03 + s13) + (s23 + s33));
    }
  }
  __syncthreads();

  // ---- 5) f32 sums -> bf16 mean rows in hsAll (over dead lsrc) ----
  {
    const int nd = tid >> 3;          // 0..127; 98 live rows, 8 chunks each
    const int ch = tid & 7;
    if (nd < kBucketNodes) {
      const int dg = lofs[nd + 1] - lofs[nd];
      const float inv = 1.0f / (float)(dg > 1 ? dg : 1);
      const int* arow = accum + nd * kAccStride + ch * 8;
      const int4 pa = *(const int4*)(arow);
      const int4 pb = *(const int4*)(arow + 4);
      unsigned h0 = bf16rne(__int_as_float(pa.x) * inv);
      unsigned h1 = bf16rne(__int_as_float(pa.y) * inv);
      unsigned h2 = bf16rne(__int_as_float(pa.z) * inv);
      unsigned h3 = bf16rne(__int_as_float(pa.w) * inv);
      unsigned h4 = bf16rne(__int_as_float(pb.x) * inv);
      unsigned h5 = bf16rne(__int_as_float(pb.y) * inv);
      unsigned h6 = bf16rne(__int_as_float(pb.z) * inv);
      unsigned h7 = bf16rne(__int_as_float(pb.w) * inv);
      uint4 pk;
      pk.x = h0 | (h1 << 16);
      pk.y = h2 | (h3 << 16);
      pk.z = h4 | (h5 << 16);
      pk.w = h6 | (h7 << 16);
      *(uint4*)(hsAll + nd * 72 + ch * 8) = pk;
    } else {
      if (nd < 112) *(uint4*)(hsAll + nd * 72 + ch * 8) =
          make_uint4(0u, 0u, 0u, 0u);
    }
  }
  __syncthreads();

  // ---- 6) MFMA epilogue (waves 0..6): wave w -> locals [w*16, w*16+16) ----
  if (tid < 448) {
    const int w8   = tid >> 6;        // 0..6
    const int ln   = tid & 63;
    const int quad = ln >> 4;
    const int col  = ln & 15;
    const int n0 = bkt * kBucketNodes;

    const short8 af0 = *reinterpret_cast<const short8*>(
        hsAll + (w8 * 16 + col) * 72 + 0 * 32 + quad * 8);
    const short8 af1 = *reinterpret_cast<const short8*>(
        hsAll + (w8 * 16 + col) * 72 + 1 * 32 + quad * 8);

    #pragma unroll
    for (int ob = 0; ob < 4; ++ob) {
      const short8 bf0 = *reinterpret_cast<const short8*>(
          Wb16 + (ob * 16 + col) * 64 + 0 * 32 + quad * 8);
      const short8 bf1 = *reinterpret_cast<const short8*>(
          Wb16 + (ob * 16 + col) * 64 + 1 * 32 + quad * 8);
      floatx4 acc = {0.f, 0.f, 0.f, 0.f};
      acc = __builtin_amdgcn_mfma_f32_16x16x32_bf16(af0, bf0, acc, 0, 0, 0);
      acc = __builtin_amdgcn_mfma_f32_16x16x32_bf16(af1, bf1, acc, 0, 0, 0);

      const int o = ob * 16 + col;
      const float bo = bsh[o];
      #pragma unroll
      for (int r = 0; r < 4; ++r) {
        const int local = w8 * 16 + quad * 4 + r;
        const int node = n0 + local;
        if (local < kBucketNodes && node < kNodes) {
          const float v = acc[r] + bo;
          out[(size_t)node * 64 + o] = v > 0.0f ? v : 0.0f;
        }
      }
    }
  }
}

// ---------------------------------------------------------------------------
extern "C" void kernel_launch(void* const* d_in, const int* in_sizes, int n_in,
                              void* d_out, int out_size, void* d_ws, size_t ws_size,
                              hipStream_t stream) {
  const float* feature  = (const float*)d_in[0];
  const int*   edge_src = (const int*)  d_in[1];
  const int*   edge_dst = (const int*)  d_in[2];
  const float* W        = (const float*)d_in[3];
  const float* b        = (const float*)d_in[4];

  float* out = (float*)d_out;
  int*   ws  = (int*)d_ws;

  gcn_build<<<kBinBlocks, 1024, 0, stream>>>(feature, edge_src, edge_dst, ws);
  gcn_aggregate<<<kBuckets, 1024, 0, stream>>>(ws, W, b, out);
}

// Round 4
// 133.286 us; speedup vs baseline: 1.0331x; 1.0331x over previous
//
#include <hip/hip_runtime.h>

// GCN layer: out = relu( segment_mean(feature[edge_src], edge_dst) @ W^T + b )
// N=100000 nodes, E=1200000 edges, 64 feats in/out, all f32.
//
// Round 18: back to the measured-best pure-atomic gather (r14 structure),
// with every parallelism axis doubled. Evidence: aggregate time was invariant
// to three different phase-4 implementations (atomics / ownership / 4-wide)
// => latency-bound, not compute-bound; the variant with most outstanding
// loads measured best. Changes:
//  * uint4 chunks: 8 lanes per edge row (16B each), 64 slots per 512-thread
//    block -> ~9 serial edges/slot (was ~18), dwordx4 gather loads.
//  * 2048 buckets x 49 nodes, 512-thread blocks, ~33.5KB LDS -> 4 blocks/CU,
//    2048 blocks = 2 clean rounds of 1024 resident. Finer granularity =
//    shorter per-block barrier chains, smaller tail.
//  * Phase 4: deterministic fixed-point LDS atomicAdd (order-independent),
//    unroll 2 so loads from consecutive edges overlap.
//  * Build: stride-8 permutation (chunk c holds feats {c,8+c,...,56+c}),
//    coalesced 16B stores; 2048-bin hist + pairwise two-level shfl scan.

typedef __attribute__((ext_vector_type(8))) short short8;   // 8 bf16
typedef __attribute__((ext_vector_type(4))) float floatx4;  // MFMA acc

constexpr int kNodes = 100000;
constexpr int kEdges = 1200000;

constexpr int kBuckets = 2048;
constexpr int kBucketNodes = 49;                    // 2048*49 = 100352 >= N

constexpr int kBinBlocks = 256;
constexpr int kEdgesPerBlock = 4688;                // 256*4688 = 1200128 >= E
constexpr int kEPT = (kEdgesPerBlock + 1023) / 1024; // 5

constexpr int kCap = 1024;        // max edges/bucket (mean 586, ~18 sigma)
constexpr float kFxScale = 262144.0f;   // 2^18 fixed-point scale
constexpr int kAccStride = 68;    // 16B-aligned rows; adds at {c,8+c,...,56+c}

// Workspace layout (int elements). Total ~19.7 MB.
constexpr int kWsFeat   = 0;                        // uint4[100000*8] (12.8MB)
constexpr int kWsOff    = 3200000;                  // int[2049][256]
constexpr int kWsBinned = kWsOff + (kBuckets + 1) * kBinBlocks;

__device__ __forceinline__ unsigned bf16rne(float f) {
  unsigned u = __float_as_uint(f);
  return (u + 0x7fffu + ((u >> 16) & 1u)) >> 16;  // round-to-nearest-even
}

// ---------------------------------------------------------------------------
// Kernel 1: feature conversion + single-pass deterministic bucket binning.
// Conversion: permuted bf16 rows as uint4[8] per node — halfword w of chunk c
// stores feat[8*w + c], so each 16B chunk c = feats {c,8+c,...,56+c}.
// Binning: <=4688 edges cached in registers -> LDS 2048-bin hist (bucket =
// dst/49) -> pairwise two-level shfl exclusive scan -> offTT (transposed)
// -> rank+scatter packed words (src | dL<<17, dL<49).
// ---------------------------------------------------------------------------
__global__ __launch_bounds__(1024) void gcn_build(
    const float* __restrict__ feat,
    const int* __restrict__ src, const int* __restrict__ dst,
    int* __restrict__ ws) {
  uint4* fb16 = (uint4*)(ws + kWsFeat);
  int* offTT  = ws + kWsOff;
  int* binned = ws + kWsBinned;

  __shared__ int lhist[kBuckets];
  __shared__ int lcur[kBuckets];
  __shared__ int wsum[16];

  const int tid = threadIdx.x;
  lhist[tid] = 0;
  lhist[tid + 1024] = 0;
  __syncthreads();

  // ---- edge slice load + bucket histogram ----
  const int e0 = blockIdx.x * kEdgesPerBlock;
  const int cnt = min(kEdgesPerBlock, kEdges - e0);   // last block: 4560
  int es[kEPT], ebk[kEPT], edl[kEPT];
  #pragma unroll
  for (int k = 0; k < kEPT; ++k) {
    const int j = tid + k * 1024;
    if (j < cnt) {
      es[k] = src[e0 + j];
      const int d = dst[e0 + j];
      const int bk = d / kBucketNodes;      // magic-multiply const div
      ebk[k] = bk;
      edl[k] = d - bk * kBucketNodes;
      atomicAdd(&lhist[bk], 1);
    }
  }

  // ---- feature f32 -> permuted bf16 uint4 (overlaps hist latency) ----
  // i = node*8 + c; chunk c gathers feats {c, 8+c, ..., 56+c}.
  const int t = blockIdx.x * 1024 + tid;
  for (int i = t; i < kNodes * 8; i += kBinBlocks * 1024) {
    const float* fr = feat + (size_t)(i >> 3) * 64 + (i & 7);
    uint4 p;
    p.x = bf16rne(fr[0])  | (bf16rne(fr[8])  << 16);
    p.y = bf16rne(fr[16]) | (bf16rne(fr[24]) << 16);
    p.z = bf16rne(fr[32]) | (bf16rne(fr[40]) << 16);
    p.w = bf16rne(fr[48]) | (bf16rne(fr[56]) << 16);
    fb16[i] = p;
  }
  __syncthreads();

  // ---- pairwise two-level shfl exclusive scan over 2048 counts ----
  // thread t owns buckets {2t, 2t+1}.
  const int a  = lhist[tid * 2];
  const int b2 = lhist[tid * 2 + 1];
  const int own = a + b2;
  const int wv = tid >> 6, ln = tid & 63;
  int sc = own;
  #pragma unroll
  for (int off = 1; off < 64; off <<= 1) {
    const int v = __shfl_up(sc, off, 64);
    if (ln >= off) sc += v;
  }
  if (ln == 63) wsum[wv] = sc;            // wave totals
  __syncthreads();
  if (tid < 64) {
    int tw = (tid < 16) ? wsum[tid] : 0;
    #pragma unroll
    for (int off = 1; off < 16; off <<= 1) {
      const int v = __shfl_up(tw, off, 64);
      if (tid >= off) tw += v;
    }
    if (tid < 16) wsum[tid] = tw;          // inclusive wave prefix
  }
  __syncthreads();
  const int e0p = sc - own + (wv ? wsum[wv - 1] : 0);  // excl for bucket 2t
  lcur[tid * 2]     = e0p;
  lcur[tid * 2 + 1] = e0p + a;
  offTT[(tid * 2) * kBinBlocks + blockIdx.x]     = e0p;       // transposed
  offTT[(tid * 2 + 1) * kBinBlocks + blockIdx.x] = e0p + a;
  if (tid == 0) offTT[kBuckets * kBinBlocks + blockIdx.x] = cnt;
  __syncthreads();

  // ---- rank + scatter into this block's bucket-grouped region ----
  int* myBin = binned + blockIdx.x * kEdgesPerBlock;
  #pragma unroll
  for (int k = 0; k < kEPT; ++k) {
    const int j = tid + k * 1024;
    if (j < cnt) {
      const int pos = atomicAdd(&lcur[ebk[k]], 1);  // LDS int atomic
      myBin[pos] = es[k] | (edl[k] << 17);
    }
  }
}

// ---------------------------------------------------------------------------
// Kernel 2: one block per bucket (2048 blocks = 2 rounds of 1024 resident),
// 512 threads (8 waves), 4 blocks/CU (~33.5 KB LDS).
//  0) segment map over the 256 block regions (contiguous offTT rows,
//     in-place wave-0 shfl scan)
//  1) local-dst histogram (edge words cached in registers, <=2/thread)
//  2) wave-0 shfl scan of 64 counters (49 live) -> lofs[]
//  3) rank+scatter packed words into lsrc[] (CSR sorted by dL)
//  4) edge-parallel gather, perfect balance: slot s (of 64) owns edges
//     [sz*s/64, sz*(s+1)/64); 8 lanes/edge, one uint4 (16B) each ->
//     8 fixed-point LDS atomicAdds at {c,8+c,...,56+c}, stride 68.
//  5) accum -> bf16 mean rows in hsAll (49 rows live, 64 allocated)
//  6) MFMA epilogue (waves 0..3): 16-node tiles, guard local<49.
// ---------------------------------------------------------------------------
__global__ __launch_bounds__(512, 8) void gcn_aggregate(
    const int*   __restrict__ ws_in,
    const float* __restrict__ W,     // [64][64] row-major W[o][d]
    const float* __restrict__ b,     // [64]
    float*       __restrict__ out) { // [kNodes][64]
  const uint4* fb16 = (const uint4*)(ws_in + kWsFeat);
  const int* offTT  = ws_in + kWsOff;
  const int* binned = ws_in + kWsBinned;

  // lsrc (4KB, phases 1-4) and hsAll (9.2KB, phases 5-6) share storage.
  __shared__ __align__(16) char uShared[64 * 72 * 2];    // 9216 B
  __shared__ __align__(16) int accum[kBucketNodes * kAccStride]; // 13.3 KB
  __shared__ int    lofs[65];
  __shared__ int    lcur[64];
  __shared__ int    runL[kBinBlocks + 1];
  __shared__ int    runG[kBinBlocks];
  __shared__ ushort Wb16[64 * 64];                 // 8 KB, natural W[o][d]
  __shared__ float  bsh[64];
  int*    lsrc  = (int*)uShared;
  ushort* hsAll = (ushort*)uShared;

  const int tid = threadIdx.x;
  const int bkt = blockIdx.x;

  if (tid < 64) { lcur[tid] = 0; bsh[tid] = b[tid]; }
  for (int i = tid; i < 4096; i += 512) Wb16[i] = (ushort)bf16rne(W[i]);
  for (int i = tid; i < kBucketNodes * kAccStride; i += 512) accum[i] = 0;

  // ---- 0) segment map over the 256 block regions ----
  if (tid < kBinBlocks) {
    const int o0 = offTT[bkt * kBinBlocks + tid];         // contiguous row
    const int o1 = offTT[(bkt + 1) * kBinBlocks + tid];   // next row
    runL[tid] = o1 - o0;                                  // temp: lengths
    runG[tid] = tid * kEdgesPerBlock + o0;
  }
  __syncthreads();
  if (tid < 64) {                        // in-place wave-0 scan, 4 elems/lane
    const int base = tid * 4;
    const int v0 = runL[base], v1 = runL[base + 1];
    const int v2 = runL[base + 2], v3 = runL[base + 3];
    const int p1 = v0 + v1, p2 = p1 + v2, tot = p2 + v3;
    int sc = tot;
    #pragma unroll
    for (int off = 1; off < 64; off <<= 1) {
      const int v = __shfl_up(sc, off, 64);
      if (tid >= off) sc += v;
    }
    const int ex = sc - tot;             // exclusive prefix of lane total
    runL[base]     = ex;
    runL[base + 1] = ex + v0;
    runL[base + 2] = ex + p1;
    runL[base + 3] = ex + p2;
    if (tid == 63) runL[kBinBlocks] = sc;
  }
  __syncthreads();

  int sz = runL[kBinBlocks];
  if (sz > kCap) sz = kCap;  // never hit for this dataset

  // j -> global binned index via 8-step binary search over runL
  auto mapRead = [&](int j) -> unsigned {
    int lo = 0, hi = kBinBlocks;
    #pragma unroll
    for (int it = 0; it < 8; ++it) {
      const int mid = (lo + hi) >> 1;
      if (runL[mid] <= j) lo = mid; else hi = mid;
    }
    return (unsigned)binned[runG[lo] + (j - runL[lo])];
  };

  // ---- 1) local-dst histogram; cache edge words in registers ----
  const int j0 = tid, j1 = tid + 512;
  const bool va = j0 < sz, vb = j1 < sz;
  unsigned ea = 0, eb = 0;
  if (va) { ea = mapRead(j0); atomicAdd(&lcur[ea >> 17], 1); }
  if (vb) { eb = mapRead(j1); atomicAdd(&lcur[eb >> 17], 1); }
  __syncthreads();

  // ---- 2) exclusive scan of 64 counters by wave 0 (49 live) ----
  if (tid < 64) {
    const int own = lcur[tid];
    int s = own;
    #pragma unroll
    for (int off = 1; off < 64; off <<= 1) {
      const int v = __shfl_up(s, off, 64);
      if (tid >= off) s += v;
    }
    const int ex = s - own;
    lofs[tid] = ex;
    lcur[tid] = ex;
    if (tid == 63) lofs[64] = s;
  }
  __syncthreads();

  // ---- 3) rank + scatter into bucket-local CSR (sorted by dL) ----
  if (va) { const int p = atomicAdd(&lcur[ea >> 17], 1); lsrc[p] = (int)ea; }
  if (vb) { const int p = atomicAdd(&lcur[eb >> 17], 1); lsrc[p] = (int)eb; }
  __syncthreads();

  // ---- 4) edge-parallel bf16 gather, perfectly balanced slots ----
  const int wave = tid >> 6;
  const int lane = tid & 63;
  const int g = lane >> 3;   // slot within wave (0..7)
  const int c = lane & 7;    // 16B chunk = feats {c,8+c,...,56+c}
  {
    const int slot = wave * 8 + g;           // 0..63
    const int jb = (sz * slot) >> 6;
    const int je = (sz * (slot + 1)) >> 6;
    #pragma unroll 2
    for (int j = jb; j < je; ++j) {
      const unsigned e = (unsigned)lsrc[j];
      const uint4 v = fb16[(size_t)(e & 0x1FFFFu) * 8 + c];
      int* rp = accum + (int)(e >> 17) * kAccStride + c;
      atomicAdd(rp + 0,  (int)(__uint_as_float(v.x << 16)          * kFxScale));
      atomicAdd(rp + 8,  (int)(__uint_as_float(v.x & 0xffff0000u) * kFxScale));
      atomicAdd(rp + 16, (int)(__uint_as_float(v.y << 16)          * kFxScale));
      atomicAdd(rp + 24, (int)(__uint_as_float(v.y & 0xffff0000u) * kFxScale));
      atomicAdd(rp + 32, (int)(__uint_as_float(v.z << 16)          * kFxScale));
      atomicAdd(rp + 40, (int)(__uint_as_float(v.z & 0xffff0000u) * kFxScale));
      atomicAdd(rp + 48, (int)(__uint_as_float(v.w << 16)          * kFxScale));
      atomicAdd(rp + 56, (int)(__uint_as_float(v.w & 0xffff0000u) * kFxScale));
    }
  }
  __syncthreads();

  // ---- 5) accum -> bf16 mean rows in hsAll (over dead lsrc) ----
  {
    const int nd = tid >> 3;          // 0..63; 49 live rows, 8 chunks each
    const int ch = tid & 7;
    if (nd < kBucketNodes) {
      const int dg = lofs[nd + 1] - lofs[nd];
      const float inv = 1.0f / (kFxScale * (float)(dg > 1 ? dg : 1));
      const int* arow = accum + nd * kAccStride + ch * 8;
      const int4 pa = *(const int4*)(arow);
      const int4 pb = *(const int4*)(arow + 4);
      unsigned h0 = bf16rne((float)pa.x * inv);
      unsigned h1 = bf16rne((float)pa.y * inv);
      unsigned h2 = bf16rne((float)pa.z * inv);
      unsigned h3 = bf16rne((float)pa.w * inv);
      unsigned h4 = bf16rne((float)pb.x * inv);
      unsigned h5 = bf16rne((float)pb.y * inv);
      unsigned h6 = bf16rne((float)pb.z * inv);
      unsigned h7 = bf16rne((float)pb.w * inv);
      uint4 pk;
      pk.x = h0 | (h1 << 16);
      pk.y = h2 | (h3 << 16);
      pk.z = h4 | (h5 << 16);
      pk.w = h6 | (h7 << 16);
      *(uint4*)(hsAll + nd * 72 + ch * 8) = pk;
    } else {
      *(uint4*)(hsAll + nd * 72 + ch * 8) = make_uint4(0u, 0u, 0u, 0u);
    }
  }
  __syncthreads();

  // ---- 6) MFMA epilogue (waves 0..3): wave w -> locals [w*16, w*16+16) ----
  if (tid < 256) {
    const int w8   = tid >> 6;        // 0..3
    const int ln   = tid & 63;
    const int quad = ln >> 4;
    const int col  = ln & 15;
    const int n0 = bkt * kBucketNodes;

    const short8 af0 = *reinterpret_cast<const short8*>(
        hsAll + (w8 * 16 + col) * 72 + 0 * 32 + quad * 8);
    const short8 af1 = *reinterpret_cast<const short8*>(
        hsAll + (w8 * 16 + col) * 72 + 1 * 32 + quad * 8);

    #pragma unroll
    for (int ob = 0; ob < 4; ++ob) {
      const short8 bf0 = *reinterpret_cast<const short8*>(
          Wb16 + (ob * 16 + col) * 64 + 0 * 32 + quad * 8);
      const short8 bf1 = *reinterpret_cast<const short8*>(
          Wb16 + (ob * 16 + col) * 64 + 1 * 32 + quad * 8);
      floatx4 acc = {0.f, 0.f, 0.f, 0.f};
      acc = __builtin_amdgcn_mfma_f32_16x16x32_bf16(af0, bf0, acc, 0, 0, 0);
      acc = __builtin_amdgcn_mfma_f32_16x16x32_bf16(af1, bf1, acc, 0, 0, 0);

      const int o = ob * 16 + col;
      const float bo = bsh[o];
      #pragma unroll
      for (int r = 0; r < 4; ++r) {
        const int local = w8 * 16 + quad * 4 + r;
        const int node = n0 + local;
        if (local < kBucketNodes && node < kNodes) {
          const float v = acc[r] + bo;
          out[(size_t)node * 64 + o] = v > 0.0f ? v : 0.0f;
        }
      }
    }
  }
}

// ---------------------------------------------------------------------------
extern "C" void kernel_launch(void* const* d_in, const int* in_sizes, int n_in,
                              void* d_out, int out_size, void* d_ws, size_t ws_size,
                              hipStream_t stream) {
  const float* feature  = (const float*)d_in[0];
  const int*   edge_src = (const int*)  d_in[1];
  const int*   edge_dst = (const int*)  d_in[2];
  const float* W        = (const float*)d_in[3];
  const float* b        = (const float*)d_in[4];

  float* out = (float*)d_out;
  int*   ws  = (int*)d_ws;

  gcn_build<<<kBinBlocks, 1024, 0, stream>>>(feature, edge_src, edge_dst, ws);
  gcn_aggregate<<<kBuckets, 512, 0, stream>>>(ws, W, b, out);
}

// Round 5
// 131.443 us; speedup vs baseline: 1.0476x; 1.0140x over previous
//
#include <hip/hip_runtime.h>

// GCN layer: out = relu( segment_mean(feature[edge_src], edge_dst) @ W^T + b )
// N=100000 nodes, E=1200000 edges, 64 feats in/out, all f32.
//
// Round 19: src-sweep gather ordering. r16 PMC: FETCH_SIZE=78.5MB vs 12.8MB
// fb16 table => half of all degree-12 row re-reads miss L2 (random src order
// spreads a row's uses across the kernel + 8 incoherent XCD L2s). Phase 4
// (fixed-point int atomics) is order-independent, so the in-bucket counting
// sort now keys on SRC-WINDOW (src>>11, 2048-node/256KB windows) instead of
// dL; degrees for the mean come from a plain deg[dL] histogram (no scan).
// Phase 4 walks edges lane-strided (j=slot; j+=64): all 64 slots and all
// ~1024 resident blocks sweep fb16 0->100K in loose lockstep => row re-reads
// become L2/L3 hits. Predicted: aggregate FETCH 78->~30MB, 44->~32us.
// Everything else = r18 (uint4 8-lane gather, 2048 buckets x 49 nodes,
// 512-thread blocks, 4/CU; build unchanged).

typedef __attribute__((ext_vector_type(8))) short short8;   // 8 bf16
typedef __attribute__((ext_vector_type(4))) float floatx4;  // MFMA acc

constexpr int kNodes = 100000;
constexpr int kEdges = 1200000;

constexpr int kBuckets = 2048;
constexpr int kBucketNodes = 49;                    // 2048*49 = 100352 >= N

constexpr int kBinBlocks = 256;
constexpr int kEdgesPerBlock = 4688;                // 256*4688 = 1200128 >= E
constexpr int kEPT = (kEdgesPerBlock + 1023) / 1024; // 5

constexpr int kCap = 1024;        // max edges/bucket (mean 586, ~18 sigma)
constexpr float kFxScale = 262144.0f;   // 2^18 fixed-point scale
constexpr int kAccStride = 68;    // 16B-aligned rows; adds at {c,8+c,...,56+c}

// Workspace layout (int elements). Total ~19.7 MB.
constexpr int kWsFeat   = 0;                        // uint4[100000*8] (12.8MB)
constexpr int kWsOff    = 3200000;                  // int[2049][256]
constexpr int kWsBinned = kWsOff + (kBuckets + 1) * kBinBlocks;

__device__ __forceinline__ unsigned bf16rne(float f) {
  unsigned u = __float_as_uint(f);
  return (u + 0x7fffu + ((u >> 16) & 1u)) >> 16;  // round-to-nearest-even
}

// ---------------------------------------------------------------------------
// Kernel 1: feature conversion + single-pass deterministic bucket binning.
// Conversion: permuted bf16 rows as uint4[8] per node — halfword w of chunk c
// stores feat[8*w + c], so each 16B chunk c = feats {c,8+c,...,56+c}.
// Binning: <=4688 edges cached in registers -> LDS 2048-bin hist (bucket =
// dst/49) -> pairwise two-level shfl exclusive scan -> offTT (transposed)
// -> rank+scatter packed words (src | dL<<17, dL<49).
// ---------------------------------------------------------------------------
__global__ __launch_bounds__(1024) void gcn_build(
    const float* __restrict__ feat,
    const int* __restrict__ src, const int* __restrict__ dst,
    int* __restrict__ ws) {
  uint4* fb16 = (uint4*)(ws + kWsFeat);
  int* offTT  = ws + kWsOff;
  int* binned = ws + kWsBinned;

  __shared__ int lhist[kBuckets];
  __shared__ int lcur[kBuckets];
  __shared__ int wsum[16];

  const int tid = threadIdx.x;
  lhist[tid] = 0;
  lhist[tid + 1024] = 0;
  __syncthreads();

  // ---- edge slice load + bucket histogram ----
  const int e0 = blockIdx.x * kEdgesPerBlock;
  const int cnt = min(kEdgesPerBlock, kEdges - e0);   // last block: 4560
  int es[kEPT], ebk[kEPT], edl[kEPT];
  #pragma unroll
  for (int k = 0; k < kEPT; ++k) {
    const int j = tid + k * 1024;
    if (j < cnt) {
      es[k] = src[e0 + j];
      const int d = dst[e0 + j];
      const int bk = d / kBucketNodes;      // magic-multiply const div
      ebk[k] = bk;
      edl[k] = d - bk * kBucketNodes;
      atomicAdd(&lhist[bk], 1);
    }
  }

  // ---- feature f32 -> permuted bf16 uint4 (overlaps hist latency) ----
  // i = node*8 + c; chunk c gathers feats {c, 8+c, ..., 56+c}.
  const int t = blockIdx.x * 1024 + tid;
  for (int i = t; i < kNodes * 8; i += kBinBlocks * 1024) {
    const float* fr = feat + (size_t)(i >> 3) * 64 + (i & 7);
    uint4 p;
    p.x = bf16rne(fr[0])  | (bf16rne(fr[8])  << 16);
    p.y = bf16rne(fr[16]) | (bf16rne(fr[24]) << 16);
    p.z = bf16rne(fr[32]) | (bf16rne(fr[40]) << 16);
    p.w = bf16rne(fr[48]) | (bf16rne(fr[56]) << 16);
    fb16[i] = p;
  }
  __syncthreads();

  // ---- pairwise two-level shfl exclusive scan over 2048 counts ----
  // thread t owns buckets {2t, 2t+1}.
  const int a  = lhist[tid * 2];
  const int b2 = lhist[tid * 2 + 1];
  const int own = a + b2;
  const int wv = tid >> 6, ln = tid & 63;
  int sc = own;
  #pragma unroll
  for (int off = 1; off < 64; off <<= 1) {
    const int v = __shfl_up(sc, off, 64);
    if (ln >= off) sc += v;
  }
  if (ln == 63) wsum[wv] = sc;            // wave totals
  __syncthreads();
  if (tid < 64) {
    int tw = (tid < 16) ? wsum[tid] : 0;
    #pragma unroll
    for (int off = 1; off < 16; off <<= 1) {
      const int v = __shfl_up(tw, off, 64);
      if (tid >= off) tw += v;
    }
    if (tid < 16) wsum[tid] = tw;          // inclusive wave prefix
  }
  __syncthreads();
  const int e0p = sc - own + (wv ? wsum[wv - 1] : 0);  // excl for bucket 2t
  lcur[tid * 2]     = e0p;
  lcur[tid * 2 + 1] = e0p + a;
  offTT[(tid * 2) * kBinBlocks + blockIdx.x]     = e0p;       // transposed
  offTT[(tid * 2 + 1) * kBinBlocks + blockIdx.x] = e0p + a;
  if (tid == 0) offTT[kBuckets * kBinBlocks + blockIdx.x] = cnt;
  __syncthreads();

  // ---- rank + scatter into this block's bucket-grouped region ----
  int* myBin = binned + blockIdx.x * kEdgesPerBlock;
  #pragma unroll
  for (int k = 0; k < kEPT; ++k) {
    const int j = tid + k * 1024;
    if (j < cnt) {
      const int pos = atomicAdd(&lcur[ebk[k]], 1);  // LDS int atomic
      myBin[pos] = es[k] | (edl[k] << 17);
    }
  }
}

// ---------------------------------------------------------------------------
// Kernel 2: one block per bucket (2048 blocks = 2 rounds of 1024 resident),
// 512 threads (8 waves), 4 blocks/CU (~33 KB LDS).
//  0) segment map over the 256 block regions (contiguous offTT rows)
//  1) dual histogram: deg[dL] (for means) + sh[src>>11] (sort key);
//     edge words cached in registers, <=2/thread
//  2) wave-0 shfl exclusive scan of the 64 src-window counters
//  3) rank+scatter into lsrc[] grouped by src-window (ascending src sweep)
//  4) lane-strided sweep gather: slot s handles j = s, s+64, ... over the
//     src-sorted list; 8 lanes/edge, one uint4 (16B) each -> 8 fixed-point
//     LDS atomicAdds at {c,8+c,...,56+c}, stride 68. All blocks sweep fb16
//     low->high src together => L2/L3-resident re-reads.
//  5) accum -> bf16 mean rows via deg[] in hsAll (49 live, 64 allocated)
//  6) MFMA epilogue (waves 0..3): 16-node tiles, guard local<49.
// ---------------------------------------------------------------------------
__global__ __launch_bounds__(512, 8) void gcn_aggregate(
    const int*   __restrict__ ws_in,
    const float* __restrict__ W,     // [64][64] row-major W[o][d]
    const float* __restrict__ b,     // [64]
    float*       __restrict__ out) { // [kNodes][64]
  const uint4* fb16 = (const uint4*)(ws_in + kWsFeat);
  const int* offTT  = ws_in + kWsOff;
  const int* binned = ws_in + kWsBinned;

  // lsrc (4KB, phases 1-4) and hsAll (9.2KB, phases 5-6) share storage.
  __shared__ __align__(16) char uShared[64 * 72 * 2];    // 9216 B
  __shared__ __align__(16) int accum[kBucketNodes * kAccStride]; // 13.3 KB
  __shared__ int    deg[64];                       // per-dL degree
  __shared__ int    sh[64];                        // src-window hist -> cur
  __shared__ int    runL[kBinBlocks + 1];
  __shared__ int    runG[kBinBlocks];
  __shared__ ushort Wb16[64 * 64];                 // 8 KB, natural W[o][d]
  __shared__ float  bsh[64];
  int*    lsrc  = (int*)uShared;
  ushort* hsAll = (ushort*)uShared;

  const int tid = threadIdx.x;
  const int bkt = blockIdx.x;

  if (tid < 64) { deg[tid] = 0; sh[tid] = 0; bsh[tid] = b[tid]; }
  for (int i = tid; i < 4096; i += 512) Wb16[i] = (ushort)bf16rne(W[i]);
  for (int i = tid; i < kBucketNodes * kAccStride; i += 512) accum[i] = 0;

  // ---- 0) segment map over the 256 block regions ----
  if (tid < kBinBlocks) {
    const int o0 = offTT[bkt * kBinBlocks + tid];         // contiguous row
    const int o1 = offTT[(bkt + 1) * kBinBlocks + tid];   // next row
    runL[tid] = o1 - o0;                                  // temp: lengths
    runG[tid] = tid * kEdgesPerBlock + o0;
  }
  __syncthreads();
  if (tid < 64) {                        // in-place wave-0 scan, 4 elems/lane
    const int base = tid * 4;
    const int v0 = runL[base], v1 = runL[base + 1];
    const int v2 = runL[base + 2], v3 = runL[base + 3];
    const int p1 = v0 + v1, p2 = p1 + v2, tot = p2 + v3;
    int sc = tot;
    #pragma unroll
    for (int off = 1; off < 64; off <<= 1) {
      const int v = __shfl_up(sc, off, 64);
      if (tid >= off) sc += v;
    }
    const int ex = sc - tot;             // exclusive prefix of lane total
    runL[base]     = ex;
    runL[base + 1] = ex + v0;
    runL[base + 2] = ex + p1;
    runL[base + 3] = ex + p2;
    if (tid == 63) runL[kBinBlocks] = sc;
  }
  __syncthreads();

  int sz = runL[kBinBlocks];
  if (sz > kCap) sz = kCap;  // never hit for this dataset

  // j -> global binned index via 8-step binary search over runL
  auto mapRead = [&](int j) -> unsigned {
    int lo = 0, hi = kBinBlocks;
    #pragma unroll
    for (int it = 0; it < 8; ++it) {
      const int mid = (lo + hi) >> 1;
      if (runL[mid] <= j) lo = mid; else hi = mid;
    }
    return (unsigned)binned[runG[lo] + (j - runL[lo])];
  };

  // ---- 1) dual histogram (degree + src-window); cache edge words ----
  const int j0 = tid, j1 = tid + 512;
  const bool va = j0 < sz, vb = j1 < sz;
  unsigned ea = 0, eb = 0;
  if (va) {
    ea = mapRead(j0);
    atomicAdd(&deg[ea >> 17], 1);
    atomicAdd(&sh[(ea & 0x1FFFFu) >> 11], 1);
  }
  if (vb) {
    eb = mapRead(j1);
    atomicAdd(&deg[eb >> 17], 1);
    atomicAdd(&sh[(eb & 0x1FFFFu) >> 11], 1);
  }
  __syncthreads();

  // ---- 2) exclusive scan of 64 src-window counters by wave 0 ----
  if (tid < 64) {
    const int own = sh[tid];
    int s = own;
    #pragma unroll
    for (int off = 1; off < 64; off <<= 1) {
      const int v = __shfl_up(s, off, 64);
      if (tid >= off) s += v;
    }
    sh[tid] = s - own;                   // exclusive; becomes running cursor
  }
  __syncthreads();

  // ---- 3) rank + scatter grouped by src-window (ascending src sweep) ----
  if (va) { const int p = atomicAdd(&sh[(ea & 0x1FFFFu) >> 11], 1); lsrc[p] = (int)ea; }
  if (vb) { const int p = atomicAdd(&sh[(eb & 0x1FFFFu) >> 11], 1); lsrc[p] = (int)eb; }
  __syncthreads();

  // ---- 4) lane-strided sweep gather, fixed-point LDS atomics ----
  const int wave = tid >> 6;
  const int lane = tid & 63;
  const int g = lane >> 3;   // slot within wave (0..7)
  const int c = lane & 7;    // 16B chunk = feats {c,8+c,...,56+c}
  {
    const int slot = wave * 8 + g;           // 0..63
    #pragma unroll 2
    for (int j = slot; j < sz; j += 64) {    // whole block walks in src order
      const unsigned e = (unsigned)lsrc[j];
      const uint4 v = fb16[(size_t)(e & 0x1FFFFu) * 8 + c];
      int* rp = accum + (int)(e >> 17) * kAccStride + c;
      atomicAdd(rp + 0,  (int)(__uint_as_float(v.x << 16)          * kFxScale));
      atomicAdd(rp + 8,  (int)(__uint_as_float(v.x & 0xffff0000u) * kFxScale));
      atomicAdd(rp + 16, (int)(__uint_as_float(v.y << 16)          * kFxScale));
      atomicAdd(rp + 24, (int)(__uint_as_float(v.y & 0xffff0000u) * kFxScale));
      atomicAdd(rp + 32, (int)(__uint_as_float(v.z << 16)          * kFxScale));
      atomicAdd(rp + 40, (int)(__uint_as_float(v.z & 0xffff0000u) * kFxScale));
      atomicAdd(rp + 48, (int)(__uint_as_float(v.w << 16)          * kFxScale));
      atomicAdd(rp + 56, (int)(__uint_as_float(v.w & 0xffff0000u) * kFxScale));
    }
  }
  __syncthreads();

  // ---- 5) accum -> bf16 mean rows via deg[] (over dead lsrc) ----
  {
    const int nd = tid >> 3;          // 0..63; 49 live rows, 8 chunks each
    const int ch = tid & 7;
    if (nd < kBucketNodes) {
      const int dg = deg[nd];
      const float inv = 1.0f / (kFxScale * (float)(dg > 1 ? dg : 1));
      const int* arow = accum + nd * kAccStride + ch * 8;
      const int4 pa = *(const int4*)(arow);
      const int4 pb = *(const int4*)(arow + 4);
      unsigned h0 = bf16rne((float)pa.x * inv);
      unsigned h1 = bf16rne((float)pa.y * inv);
      unsigned h2 = bf16rne((float)pa.z * inv);
      unsigned h3 = bf16rne((float)pa.w * inv);
      unsigned h4 = bf16rne((float)pb.x * inv);
      unsigned h5 = bf16rne((float)pb.y * inv);
      unsigned h6 = bf16rne((float)pb.z * inv);
      unsigned h7 = bf16rne((float)pb.w * inv);
      uint4 pk;
      pk.x = h0 | (h1 << 16);
      pk.y = h2 | (h3 << 16);
      pk.z = h4 | (h5 << 16);
      pk.w = h6 | (h7 << 16);
      *(uint4*)(hsAll + nd * 72 + ch * 8) = pk;
    } else {
      *(uint4*)(hsAll + nd * 72 + ch * 8) = make_uint4(0u, 0u, 0u, 0u);
    }
  }
  __syncthreads();

  // ---- 6) MFMA epilogue (waves 0..3): wave w -> locals [w*16, w*16+16) ----
  if (tid < 256) {
    const int w8   = tid >> 6;        // 0..3
    const int ln   = tid & 63;
    const int quad = ln >> 4;
    const int col  = ln & 15;
    const int n0 = bkt * kBucketNodes;

    const short8 af0 = *reinterpret_cast<const short8*>(
        hsAll + (w8 * 16 + col) * 72 + 0 * 32 + quad * 8);
    const short8 af1 = *reinterpret_cast<const short8*>(
        hsAll + (w8 * 16 + col) * 72 + 1 * 32 + quad * 8);

    #pragma unroll
    for (int ob = 0; ob < 4; ++ob) {
      const short8 bf0 = *reinterpret_cast<const short8*>(
          Wb16 + (ob * 16 + col) * 64 + 0 * 32 + quad * 8);
      const short8 bf1 = *reinterpret_cast<const short8*>(
          Wb16 + (ob * 16 + col) * 64 + 1 * 32 + quad * 8);
      floatx4 acc = {0.f, 0.f, 0.f, 0.f};
      acc = __builtin_amdgcn_mfma_f32_16x16x32_bf16(af0, bf0, acc, 0, 0, 0);
      acc = __builtin_amdgcn_mfma_f32_16x16x32_bf16(af1, bf1, acc, 0, 0, 0);

      const int o = ob * 16 + col;
      const float bo = bsh[o];
      #pragma unroll
      for (int r = 0; r < 4; ++r) {
        const int local = w8 * 16 + quad * 4 + r;
        const int node = n0 + local;
        if (local < kBucketNodes && node < kNodes) {
          const float v = acc[r] + bo;
          out[(size_t)node * 64 + o] = v > 0.0f ? v : 0.0f;
        }
      }
    }
  }
}

// ---------------------------------------------------------------------------
extern "C" void kernel_launch(void* const* d_in, const int* in_sizes, int n_in,
                              void* d_out, int out_size, void* d_ws, size_t ws_size,
                              hipStream_t stream) {
  const float* feature  = (const float*)d_in[0];
  const int*   edge_src = (const int*)  d_in[1];
  const int*   edge_dst = (const int*)  d_in[2];
  const float* W        = (const float*)d_in[3];
  const float* b        = (const float*)d_in[4];

  float* out = (float*)d_out;
  int*   ws  = (int*)d_ws;

  gcn_build<<<kBinBlocks, 1024, 0, stream>>>(feature, edge_src, edge_dst, ws);
  gcn_aggregate<<<kBuckets, 512, 0, stream>>>(ws, W, b, out);
}